// Round 4
// baseline (644.092 us; speedup 1.0000x reference)
//
#include <hip/hip_runtime.h>
#include <hip/hip_bf16.h>
#include <cstdint>
#include <cstddef>

// Problem constants (Qwen2: B=2,S=4096,H=3584,NH=28,NKV=4,D=128)
#define SS 4096
#define HH 3584
#define NHQ 28
#define NKVH 4
#define DD 128
#define MM 8192                 // B*S
#define NN 4608                 // (NH+2*NKV)*D
#define KK 3584
#define QOFF 0
#define KOFF 29360128ULL        // B*NH*S*D
#define VOFF 33554432ULL        // KOFF + B*NKV*S*D

// GEMM: 256x256 tile, BK=64/K-tile, 2 K-tiles per 8-phase iteration.
// 8 waves (2M x 4N), wave tile 128x64 (RoPE-paired cols).
// LDS: 8 slots x 16KB ([128 rows][64 k], 128B rows - proven 0-conflict).
#define BM 256
#define BN 256
#define NIT 28                  // KK/128
#define NBN3 18                 // NN/BN
#define GRID_GEMM 576           // 32*18, %8==0 -> bijective XCD swizzle

// prep block ranges
#define NB_CVT 7168             // MM*KK/16/256
#define NB_TQ 3136              // (3584/64)*(3584/64)
#define NB_TK 448               // (512/64)*(3584/64)
#define NB_PREP (NB_CVT + NB_TQ + 2 * NB_TK)

typedef __bf16 bf16;
typedef bf16  bf16x8  __attribute__((ext_vector_type(8)));
typedef float floatx4 __attribute__((ext_vector_type(4)));

// ------------------------------------------------------------- fused prep ---
__global__ __launch_bounds__(256) void prep(
    const float* __restrict__ hs, const float* __restrict__ Wq,
    const float* __restrict__ Wk, const float* __restrict__ Wv,
    bf16* __restrict__ Abf, bf16* __restrict__ Bt) {

    int blk = blockIdx.x;
    if (blk < NB_CVT) {
        size_t i = (size_t)blk * 256 + threadIdx.x;      // 16 floats per thread
        const float4* s = (const float4*)hs;
        float4 a = s[4 * i], b = s[4 * i + 1], c = s[4 * i + 2], d = s[4 * i + 3];
        bf16x8 o0, o1;
        o0[0] = (bf16)a.x; o0[1] = (bf16)a.y; o0[2] = (bf16)a.z; o0[3] = (bf16)a.w;
        o0[4] = (bf16)b.x; o0[5] = (bf16)b.y; o0[6] = (bf16)b.z; o0[7] = (bf16)b.w;
        o1[0] = (bf16)c.x; o1[1] = (bf16)c.y; o1[2] = (bf16)c.z; o1[3] = (bf16)c.w;
        o1[4] = (bf16)d.x; o1[5] = (bf16)d.y; o1[6] = (bf16)d.z; o1[7] = (bf16)d.w;
        *(bf16x8*)(Abf + i * 16)     = o0;
        *(bf16x8*)(Abf + i * 16 + 8) = o1;
        return;
    }
    // ---- transpose part: 64x64 fp32 tile -> Bt (n,k) bf16 ----
    const float* W; int ncols, row_off, nb, kb;
    int t = blk - NB_CVT;
    if (t < NB_TQ)            { W = Wq; ncols = 3584; row_off = 0;    nb = t % 56; kb = t / 56; }
    else if (t < NB_TQ+NB_TK) { int u = t - NB_TQ;         W = Wk; ncols = 512; row_off = 3584; nb = u % 8; kb = u / 8; }
    else                      { int u = t - NB_TQ - NB_TK; W = Wv; ncols = 512; row_off = 4096; nb = u % 8; kb = u / 8; }

    __shared__ float tile[64][65];
    int n0 = nb * 64, k0 = kb * 64;
    int c4 = threadIdx.x & 15;          // float4 column
    int rr = threadIdx.x >> 4;          // 0..15
#pragma unroll
    for (int i = 0; i < 4; ++i) {
        int row = i * 16 + rr;
        float4 v = *(const float4*)(W + (size_t)(k0 + row) * ncols + n0 + c4 * 4);
        tile[row][c4 * 4 + 0] = v.x;
        tile[row][c4 * 4 + 1] = v.y;
        tile[row][c4 * 4 + 2] = v.z;
        tile[row][c4 * 4 + 3] = v.w;
    }
    __syncthreads();
    int kc  = threadIdx.x & 7;          // 16B k-chunk
    int nr0 = threadIdx.x >> 3;         // 0..31
#pragma unroll
    for (int cc = 0; cc < 2; ++cc) {
        int nrow = nr0 + cc * 32;
        bf16x8 o;
#pragma unroll
        for (int j = 0; j < 8; ++j) o[j] = (bf16)tile[kc * 8 + j][nrow];
        *(bf16x8*)(Bt + (size_t)(row_off + n0 + nrow) * KK + k0 + kc * 8) = o;
    }
}

// ----------------------------------------------------------------- GEMM -----
__device__ __forceinline__ void g2l16(const void* g, void* l) {
    __builtin_amdgcn_global_load_lds(
        (const __attribute__((address_space(1))) void*)g,
        (__attribute__((address_space(3))) void*)l, 16, 0, 0);
}

// Slot map (16KB each): slot = par*4 + op*2 + half.
//   A slot (op=0) half=mh: global rows {l*128 + mh*64 + r}, slot-row = l*64+r
//   B slot (op=1) half=x : global cols {l*128 + x*64  + c}, slot-row = l*64+c
// Stage one slot: 2 x g2l16/thread. Source chunk pre-swizzled by (row&7).
#define STAGE(ptr, slot, half, kb) do {                                       \
    g2l16((ptr) + (size_t)((half) * 64) * KK + (kb),                          \
          ldsB + (slot) * 16384 + tid * 16);                                  \
    g2l16((ptr) + (size_t)((half) * 64 + 128) * KK + (kb),                    \
          ldsB + (slot) * 16384 + 8192 + tid * 16);                           \
} while (0)

#define VM(n) asm volatile("s_waitcnt vmcnt(" #n ")" ::: "memory")

// Phase (PAR, MH, X): 12 ds_read_b128 | stage 1 slot | counted wait | barrier |
// lgkmcnt(0) | setprio(1) 16 MFMA setprio(0) | barrier
#define PH(PAR, MH, X, STG, WT) do {                                          \
    const char* aS = ldsC + ((PAR) * 4 + (MH)) * 16384;                       \
    const char* bS = ldsC + ((PAR) * 4 + 2 + (X)) * 16384;                    \
    bf16x8 a0[4], a1[4], b0[2], b1[2];                                        \
    _Pragma("unroll")                                                         \
    for (int m4 = 0; m4 < 4; ++m4) {                                          \
        a0[m4] = *(const bf16x8*)(aS + (aRd + m4 * 2048));                    \
        a1[m4] = *(const bf16x8*)(aS + ((aRd + m4 * 2048) ^ 64));             \
    }                                                                         \
    _Pragma("unroll")                                                         \
    for (int p = 0; p < 2; ++p) {                                             \
        b0[p] = *(const bf16x8*)(bS + (bRd + p * 2048));                      \
        b1[p] = *(const bf16x8*)(bS + ((bRd + p * 2048) ^ 64));               \
    }                                                                         \
    STG;                                                                      \
    WT;                                                                       \
    __builtin_amdgcn_s_barrier();                                             \
    asm volatile("s_waitcnt lgkmcnt(0)" ::: "memory");                        \
    __builtin_amdgcn_s_setprio(1);                                            \
    _Pragma("unroll")                                                         \
    for (int m4 = 0; m4 < 4; ++m4)                                            \
        _Pragma("unroll")                                                     \
        for (int p = 0; p < 2; ++p) {                                         \
            acc[(MH)*4 + m4][2*p + (X)] =                                     \
                __builtin_amdgcn_mfma_f32_16x16x32_bf16(                      \
                    a0[m4], b0[p], acc[(MH)*4 + m4][2*p + (X)], 0, 0, 0);     \
            acc[(MH)*4 + m4][2*p + (X)] =                                     \
                __builtin_amdgcn_mfma_f32_16x16x32_bf16(                      \
                    a1[m4], b1[p], acc[(MH)*4 + m4][2*p + (X)], 0, 0, 0);     \
        }                                                                     \
    __builtin_amdgcn_s_setprio(0);                                            \
    __builtin_amdgcn_s_barrier();                                             \
} while (0)

__global__ __launch_bounds__(512, 2) void qkv_gemm(
    const bf16* __restrict__ A, const bf16* __restrict__ Bt,
    const float* __restrict__ bq, const float* __restrict__ bk,
    const float* __restrict__ bv, const float* __restrict__ cosp,
    const float* __restrict__ sinp, float* __restrict__ out) {

    __shared__ __align__(16) bf16 lds[8 * 8192];    // 8 slots x 16KB = 128KB

    const int tid  = threadIdx.x;
    const int lane = tid & 63;
    const int wave = tid >> 6;          // 0..7
    const int wm   = wave >> 2;         // M-half: rows wm*128..+127
    const int wn   = wave & 3;
    const int hh   = wn >> 1;           // head within 256-col tile
    const int pw   = wn & 1;            // 32-col slice within head

    // bijective XCD swizzle (GRID_GEMM % 8 == 0)
    const int wg = (blockIdx.x & 7) * (GRID_GEMM / 8) + (blockIdx.x >> 3);
    const int bm = wg / NBN3;
    const int bn = wg % NBN3;
    const int m0 = bm * BM;
    const int n0 = bn * BN;

    // staging thread base: row/col (tid>>3) in [0,64), swizzled 16B chunk
    const int sRow = tid >> 3;
    const int sCh  = (tid & 7) ^ (sRow & 7);
    const bf16* aB = A  + (size_t)(m0 + sRow) * KK + sCh * 8;
    const bf16* bB = Bt + (size_t)(n0 + sRow) * KK + sCh * 8;
    char* ldsB = (char*)lds;
    const char* ldsC = (const char*)lds;

    // fragment read offsets: slot-row*128 + (fq ^ (row&7))*16  (row&7 == fr&7)
    const int fr  = lane & 15;
    const int fq  = lane >> 4;
    const int aRd = (wm * 64 + fr) * 128 + (fq ^ (fr & 7)) * 16;
    const int bRd = (hh * 64 + pw * 32 + fr) * 128 + (fq ^ (fr & 7)) * 16;

    floatx4 acc[8][4];
#pragma unroll
    for (int mi = 0; mi < 8; ++mi)
#pragma unroll
        for (int ni = 0; ni < 4; ++ni)
            acc[mi][ni] = (floatx4){0.f, 0.f, 0.f, 0.f};

    // ---- prologue: t0 all 4 slots + t1 A.lo/B.lo; land first 4 units
    STAGE(aB, 0, 0, 0);     // t0 A.lo
    STAGE(bB, 2, 0, 0);     // t0 B.lo
    STAGE(aB, 1, 1, 0);     // t0 A.hi
    STAGE(bB, 3, 1, 0);     // t0 B.hi
    STAGE(aB, 4, 0, 64);    // t1 A.lo
    STAGE(bB, 6, 0, 64);    // t1 B.lo
    VM(4);
    __builtin_amdgcn_s_barrier();

    // ---- main loop: 8 phases over 2 K-tiles; 1 slot staged per phase.
    // Waits: P1 vm(6), P4 vm(8), P5 vm(6), P8 vm(8)  (counted, never 0).
    for (int j = 0; j < NIT - 1; ++j) {
        const int kb1 = j * 128 + 64;    // tile 2j+1
        const int kn0 = j * 128 + 128;   // tile 2j+2
        const int kn1 = j * 128 + 192;   // tile 2j+3
        PH(0, 0, 0, STAGE(aB, 5, 1, kb1), VM(6));   // P1: stage t1.A.hi
        PH(0, 0, 1, STAGE(bB, 7, 1, kb1), (void)0); // P2: stage t1.B.hi
        PH(0, 1, 0, STAGE(aB, 0, 0, kn0), (void)0); // P3: stage t2.A.lo
        PH(0, 1, 1, STAGE(bB, 2, 0, kn0), VM(8));   // P4: stage t2.B.lo
        PH(1, 0, 0, STAGE(aB, 1, 1, kn0), VM(6));   // P5: stage t2.A.hi
        PH(1, 0, 1, STAGE(bB, 3, 1, kn0), (void)0); // P6: stage t2.B.hi
        PH(1, 1, 0, STAGE(aB, 4, 0, kn1), (void)0); // P7: stage t3.A.lo
        PH(1, 1, 1, STAGE(bB, 6, 0, kn1), VM(8));   // P8: stage t3.B.lo
    }
    // ---- last iteration (j = NIT-1): only t_last hi-halves still to stage
    PH(0, 0, 0, STAGE(aB, 5, 1, KK - 64), VM(6));
    PH(0, 0, 1, STAGE(bB, 7, 1, KK - 64), (void)0);
    PH(0, 1, 0, (void)0, (void)0);
    PH(0, 1, 1, (void)0, VM(4));
    PH(1, 0, 0, (void)0, VM(0));
    PH(1, 0, 1, (void)0, (void)0);
    PH(1, 1, 0, (void)0, (void)0);
    PH(1, 1, 1, (void)0, (void)0);

    // ---- epilogue: bias + RoPE (register-local pairs) + permuted store -----
    const float* bias;
    int hbase, nh;
    size_t obase;
    bool rope;
    if (n0 < 3584)      { bias = bq + n0;          hbase = n0 >> 7;          obase = QOFF; nh = NHQ;  rope = true;  }
    else if (n0 < 4096) { bias = bk + (n0 - 3584); hbase = (n0 - 3584) >> 7; obase = KOFF; nh = NKVH; rope = true;  }
    else                { bias = bv + (n0 - 4096); hbase = (n0 - 4096) >> 7; obase = VOFF; nh = NKVH; rope = false; }
    const int h = hbase + hh;

    float blo[2], bhi[2];
#pragma unroll
    for (int p = 0; p < 2; ++p) {
        int d = pw * 32 + p * 16 + fr;     // in [0,64)
        blo[p] = bias[hh * 128 + d];
        bhi[p] = bias[hh * 128 + d + 64];
    }

#pragma unroll
    for (int mi = 0; mi < 8; ++mi) {
#pragma unroll
        for (int r = 0; r < 4; ++r) {
            int m = m0 + wm * 128 + mi * 16 + fq * 4 + r;   // C/D: row=quad*4+reg
            int b = m >> 12;                                // m / S
            int s = m & 4095;                               // m % S
            size_t orow = obase + ((size_t)(b * nh + h) * SS + s) * DD;
#pragma unroll
            for (int p = 0; p < 2; ++p) {
                int d = pw * 32 + p * 16 + fr;
                float xlo = acc[mi][2 * p][r] + blo[p];
                float xhi = acc[mi][2 * p + 1][r] + bhi[p];
                float ylo, yhi;
                if (rope) {
                    float c  = cosp[(size_t)m * DD + d];
                    float sn = sinp[(size_t)m * DD + d];
                    ylo = xlo * c - xhi * sn;      // d < 64:  x*cos - x_hi*sin
                    yhi = xhi * c + xlo * sn;      // d >= 64: x*cos + x_lo*sin
                } else {
                    ylo = xlo; yhi = xhi;
                }
                out[orow + d]      = ylo;
                out[orow + d + 64] = yhi;
            }
        }
    }
}

// ---------------------------------------------------------------- launch ----
extern "C" void kernel_launch(void* const* d_in, const int* in_sizes, int n_in,
                              void* d_out, int out_size, void* d_ws, size_t ws_size,
                              hipStream_t stream) {
    const float* hs   = (const float*)d_in[0];
    const float* cosp = (const float*)d_in[1];
    const float* sinp = (const float*)d_in[2];
    const float* Wq   = (const float*)d_in[3];
    const float* bq   = (const float*)d_in[4];
    const float* Wk   = (const float*)d_in[5];
    const float* bk   = (const float*)d_in[6];
    const float* Wv   = (const float*)d_in[7];
    const float* bv   = (const float*)d_in[8];
    float* out = (float*)d_out;

    bf16* Abf = (bf16*)d_ws;                      // 8192x3584 bf16 = 58.7 MB
    bf16* Btb = Abf + (size_t)MM * KK;            // 4608x3584 bf16 = 33.0 MB

    prep<<<NB_PREP, 256, 0, stream>>>(hs, Wq, Wk, Wv, Abf, Btb);
    qkv_gemm<<<GRID_GEMM, 512, 0, stream>>>(Abf, Btb, bq, bk, bv, cosp, sinp, out);
}

// Round 5
// 604.852 us; speedup vs baseline: 1.0649x; 1.0649x over previous
//
#include <hip/hip_runtime.h>
#include <hip/hip_bf16.h>
#include <cstdint>
#include <cstddef>

// Problem constants (Qwen2: B=2,S=4096,H=3584,NH=28,NKV=4,D=128)
#define SS 4096
#define HH 3584
#define NHQ 28
#define NKVH 4
#define DD 128
#define MM 8192                 // B*S
#define NN 4608                 // (NH+2*NKV)*D
#define KK 3584
#define QOFF 0
#define KOFF 29360128ULL        // B*NH*S*D
#define VOFF 33554432ULL        // KOFF + B*NKV*S*D

// GEMM: 256x256 tile, BK=64/K-tile, 2 K-tiles per 8-phase iteration.
// 8 waves (2M x 4N), wave tile 128x64 (RoPE-paired cols).
// LDS: 8 slots x 16KB ([128 rows][64 k], 128B rows, 0-conflict swizzle).
// Read-dedup: per K-tile P1={8A.lo+4B.lo} P2={4B.hi} P3={8A.hi} P4={}
// with the K-tile's B fragments persistent in registers (24 reads/K-tile).
#define BM 256
#define BN 256
#define NIT 28                  // KK/128
#define NBN3 18                 // NN/BN
#define GRID_GEMM 576           // 32*18, %8==0 -> bijective XCD swizzle

// prep block ranges
#define NB_CVT 7168             // MM*KK/16/256
#define NB_TQ 3136              // (3584/64)*(3584/64)
#define NB_TK 448               // (512/64)*(3584/64)
#define NB_PREP (NB_CVT + NB_TQ + 2 * NB_TK)

typedef __bf16 bf16;
typedef bf16  bf16x8  __attribute__((ext_vector_type(8)));
typedef float floatx4 __attribute__((ext_vector_type(4)));

// ------------------------------------------------------------- fused prep ---
__global__ __launch_bounds__(256) void prep(
    const float* __restrict__ hs, const float* __restrict__ Wq,
    const float* __restrict__ Wk, const float* __restrict__ Wv,
    bf16* __restrict__ Abf, bf16* __restrict__ Bt) {

    int blk = blockIdx.x;
    if (blk < NB_CVT) {
        size_t i = (size_t)blk * 256 + threadIdx.x;      // 16 floats per thread
        const float4* s = (const float4*)hs;
        float4 a = s[4 * i], b = s[4 * i + 1], c = s[4 * i + 2], d = s[4 * i + 3];
        bf16x8 o0, o1;
        o0[0] = (bf16)a.x; o0[1] = (bf16)a.y; o0[2] = (bf16)a.z; o0[3] = (bf16)a.w;
        o0[4] = (bf16)b.x; o0[5] = (bf16)b.y; o0[6] = (bf16)b.z; o0[7] = (bf16)b.w;
        o1[0] = (bf16)c.x; o1[1] = (bf16)c.y; o1[2] = (bf16)c.z; o1[3] = (bf16)c.w;
        o1[4] = (bf16)d.x; o1[5] = (bf16)d.y; o1[6] = (bf16)d.z; o1[7] = (bf16)d.w;
        *(bf16x8*)(Abf + i * 16)     = o0;
        *(bf16x8*)(Abf + i * 16 + 8) = o1;
        return;
    }
    // ---- transpose part: 64x64 fp32 tile -> Bt (n,k) bf16 ----
    const float* W; int ncols, row_off, nb, kb;
    int t = blk - NB_CVT;
    if (t < NB_TQ)            { W = Wq; ncols = 3584; row_off = 0;    nb = t % 56; kb = t / 56; }
    else if (t < NB_TQ+NB_TK) { int u = t - NB_TQ;         W = Wk; ncols = 512; row_off = 3584; nb = u % 8; kb = u / 8; }
    else                      { int u = t - NB_TQ - NB_TK; W = Wv; ncols = 512; row_off = 4096; nb = u % 8; kb = u / 8; }

    __shared__ float tile[64][65];
    int n0 = nb * 64, k0 = kb * 64;
    int c4 = threadIdx.x & 15;          // float4 column
    int rr = threadIdx.x >> 4;          // 0..15
#pragma unroll
    for (int i = 0; i < 4; ++i) {
        int row = i * 16 + rr;
        float4 v = *(const float4*)(W + (size_t)(k0 + row) * ncols + n0 + c4 * 4);
        tile[row][c4 * 4 + 0] = v.x;
        tile[row][c4 * 4 + 1] = v.y;
        tile[row][c4 * 4 + 2] = v.z;
        tile[row][c4 * 4 + 3] = v.w;
    }
    __syncthreads();
    int kc  = threadIdx.x & 7;          // 16B k-chunk
    int nr0 = threadIdx.x >> 3;         // 0..31
#pragma unroll
    for (int cc = 0; cc < 2; ++cc) {
        int nrow = nr0 + cc * 32;
        bf16x8 o;
#pragma unroll
        for (int j = 0; j < 8; ++j) o[j] = (bf16)tile[kc * 8 + j][nrow];
        *(bf16x8*)(Bt + (size_t)(row_off + n0 + nrow) * KK + k0 + kc * 8) = o;
    }
}

// ----------------------------------------------------------------- GEMM -----
__device__ __forceinline__ void g2l16(const void* g, void* l) {
    __builtin_amdgcn_global_load_lds(
        (const __attribute__((address_space(1))) void*)g,
        (__attribute__((address_space(3))) void*)l, 16, 0, 0);
}

// Slot map (16KB each): slot = par*4 + op*2 + half.
//   A slot (op=0) half=mh: global rows {l*128 + mh*64 + r}, slot-row = l*64+r
//   B slot (op=1) half=x : global cols {l*128 + x*64  + c}, slot-row = l*64+c
#define STAGE(ptr, slot, half, kb) do {                                       \
    g2l16((ptr) + (size_t)((half) * 64) * KK + (kb),                          \
          ldsB + (slot) * 16384 + tid * 16);                                  \
    g2l16((ptr) + (size_t)((half) * 64 + 128) * KK + (kb),                    \
          ldsB + (slot) * 16384 + 8192 + tid * 16);                           \
} while (0)

#define VM(n) asm volatile("s_waitcnt vmcnt(" #n ")" ::: "memory")

// read helpers: fragments into persistent register arrays (static indexing)
#define RD_A(PAR, MH) do {                                                    \
    const char* aS_ = ldsC + ((PAR) * 4 + (MH)) * 16384;                      \
    _Pragma("unroll")                                                         \
    for (int m4 = 0; m4 < 4; ++m4) {                                          \
        a0[m4] = *(const bf16x8*)(aS_ + (aRd + m4 * 2048));                   \
        a1[m4] = *(const bf16x8*)(aS_ + ((aRd + m4 * 2048) ^ 64));            \
    }                                                                         \
} while (0)

#define RD_B(PAR, X, B0, B1) do {                                             \
    const char* bS_ = ldsC + ((PAR) * 4 + 2 + (X)) * 16384;                   \
    _Pragma("unroll")                                                         \
    for (int p = 0; p < 2; ++p) {                                             \
        B0[p] = *(const bf16x8*)(bS_ + (bRd + p * 2048));                     \
        B1[p] = *(const bf16x8*)(bS_ + ((bRd + p * 2048) ^ 64));              \
    }                                                                         \
} while (0)

// Phase: {reads | stage 1 slot | counted wait | barrier | lgkmcnt(0) |
//         setprio(1) 16 MFMA setprio(0) | barrier}
#define PH(MH, X, B0, B1, RD, STG, WT) do {                                   \
    RD;                                                                       \
    STG;                                                                      \
    WT;                                                                       \
    __builtin_amdgcn_s_barrier();                                             \
    asm volatile("s_waitcnt lgkmcnt(0)" ::: "memory");                        \
    __builtin_amdgcn_s_setprio(1);                                            \
    _Pragma("unroll")                                                         \
    for (int m4 = 0; m4 < 4; ++m4)                                            \
        _Pragma("unroll")                                                     \
        for (int p = 0; p < 2; ++p) {                                         \
            acc[(MH)*4 + m4][2*p + (X)] =                                     \
                __builtin_amdgcn_mfma_f32_16x16x32_bf16(                      \
                    a0[m4], B0[p], acc[(MH)*4 + m4][2*p + (X)], 0, 0, 0);     \
            acc[(MH)*4 + m4][2*p + (X)] =                                     \
                __builtin_amdgcn_mfma_f32_16x16x32_bf16(                      \
                    a1[m4], B1[p], acc[(MH)*4 + m4][2*p + (X)], 0, 0, 0);     \
        }                                                                     \
    __builtin_amdgcn_s_setprio(0);                                            \
    __builtin_amdgcn_s_barrier();                                             \
} while (0)

__global__ __launch_bounds__(512, 2) void qkv_gemm(
    const bf16* __restrict__ A, const bf16* __restrict__ Bt,
    const float* __restrict__ bq, const float* __restrict__ bk,
    const float* __restrict__ bv, const float* __restrict__ cosp,
    const float* __restrict__ sinp, float* __restrict__ out) {

    __shared__ __align__(16) bf16 lds[8 * 8192];    // 8 slots x 16KB = 128KB

    const int tid  = threadIdx.x;
    const int lane = tid & 63;
    const int wave = tid >> 6;          // 0..7
    const int wm   = wave >> 2;         // M-half: rows wm*128..+127
    const int wn   = wave & 3;
    const int hh   = wn >> 1;           // head within 256-col tile
    const int pw   = wn & 1;            // 32-col slice within head

    // bijective XCD swizzle (GRID_GEMM % 8 == 0)
    const int wg = (blockIdx.x & 7) * (GRID_GEMM / 8) + (blockIdx.x >> 3);
    const int bm = wg / NBN3;
    const int bn = wg % NBN3;
    const int m0 = bm * BM;
    const int n0 = bn * BN;

    // staging thread base: row/col (tid>>3) in [0,64), swizzled 16B chunk
    const int sRow = tid >> 3;
    const int sCh  = (tid & 7) ^ (sRow & 7);
    const bf16* aB = A  + (size_t)(m0 + sRow) * KK + sCh * 8;
    const bf16* bB = Bt + (size_t)(n0 + sRow) * KK + sCh * 8;
    char* ldsB = (char*)lds;
    const char* ldsC = (const char*)lds;

    // fragment read offsets: slot-row*128 + (fq ^ (row&7))*16  (row&7 == fr&7)
    const int fr  = lane & 15;
    const int fq  = lane >> 4;
    const int aRd = (wm * 64 + fr) * 128 + (fq ^ (fr & 7)) * 16;
    const int bRd = (hh * 64 + pw * 32 + fr) * 128 + (fq ^ (fr & 7)) * 16;

    floatx4 acc[8][4];
#pragma unroll
    for (int mi = 0; mi < 8; ++mi)
#pragma unroll
        for (int ni = 0; ni < 4; ++ni)
            acc[mi][ni] = (floatx4){0.f, 0.f, 0.f, 0.f};

    // persistent fragment registers (always statically indexed)
    bf16x8 a0[4], a1[4];                // current m-half, k-slices 0/1
    bf16x8 bl0[2], bl1[2];              // B x=0 (cols d..d+63),  k-slices 0/1
    bf16x8 bh0[2], bh1[2];              // B x=1 (cols d+64..),   k-slices 0/1

    // ---- prologue: t0 all 4 slots + t1 lo halves; land t0
    STAGE(aB, 0, 0, 0);     // t0 A.lo
    STAGE(bB, 2, 0, 0);     // t0 B.lo
    STAGE(aB, 1, 1, 0);     // t0 A.hi
    STAGE(bB, 3, 1, 0);     // t0 B.hi
    STAGE(aB, 4, 0, 64);    // t1 A.lo
    STAGE(bB, 6, 0, 64);    // t1 B.lo
    VM(4);
    __builtin_amdgcn_s_barrier();

    // ---- main loop: 2 K-tiles per iteration, 8 phases, 1 slot staged/phase.
    // Reads per K-tile: P1 12 (A.lo+B.lo), P2 4 (B.hi), P3 8 (A.hi), P4 0.
    for (int j = 0; j < NIT - 1; ++j) {
        const int kb1 = j * 128 + 64;    // tile 2j+1
        const int kn0 = j * 128 + 128;   // tile 2j+2
        const int kn1 = j * 128 + 192;   // tile 2j+3
        // par 0 (tile 2j)
        PH(0, 0, bl0, bl1, { RD_A(0,0); RD_B(0,0,bl0,bl1); }, STAGE(aB,5,1,kb1), VM(6));
        PH(0, 1, bh0, bh1, { RD_B(0,1,bh0,bh1); },            STAGE(bB,7,1,kb1), (void)0);
        PH(1, 1, bh0, bh1, { RD_A(0,1); },                    STAGE(aB,0,0,kn0), (void)0);
        PH(1, 0, bl0, bl1, { },                               STAGE(bB,2,0,kn0), VM(8));
        // par 1 (tile 2j+1)
        PH(0, 0, bl0, bl1, { RD_A(1,0); RD_B(1,0,bl0,bl1); }, STAGE(aB,1,1,kn0), VM(6));
        PH(0, 1, bh0, bh1, { RD_B(1,1,bh0,bh1); },            STAGE(bB,3,1,kn0), (void)0);
        PH(1, 1, bh0, bh1, { RD_A(1,1); },                    STAGE(aB,4,0,kn1), (void)0);
        PH(1, 0, bl0, bl1, { },                               STAGE(bB,6,0,kn1), VM(8));
    }
    // ---- last iteration (tiles 2NIT-2, 2NIT-1): stage only t_last hi halves
    PH(0, 0, bl0, bl1, { RD_A(0,0); RD_B(0,0,bl0,bl1); }, STAGE(aB,5,1,KK-64), VM(6));
    PH(0, 1, bh0, bh1, { RD_B(0,1,bh0,bh1); },            STAGE(bB,7,1,KK-64), (void)0);
    PH(1, 1, bh0, bh1, { RD_A(0,1); },                    (void)0, (void)0);
    PH(1, 0, bl0, bl1, { },                               (void)0, VM(4));
    PH(0, 0, bl0, bl1, { RD_A(1,0); RD_B(1,0,bl0,bl1); }, (void)0, VM(0));
    PH(0, 1, bh0, bh1, { RD_B(1,1,bh0,bh1); },            (void)0, (void)0);
    PH(1, 1, bh0, bh1, { RD_A(1,1); },                    (void)0, (void)0);
    PH(1, 0, bl0, bl1, { },                               (void)0, (void)0);

    // ---- epilogue: bias + RoPE (register-local pairs) + permuted store -----
    const float* bias;
    int hbase, nh;
    size_t obase;
    bool rope;
    if (n0 < 3584)      { bias = bq + n0;          hbase = n0 >> 7;          obase = QOFF; nh = NHQ;  rope = true;  }
    else if (n0 < 4096) { bias = bk + (n0 - 3584); hbase = (n0 - 3584) >> 7; obase = KOFF; nh = NKVH; rope = true;  }
    else                { bias = bv + (n0 - 4096); hbase = (n0 - 4096) >> 7; obase = VOFF; nh = NKVH; rope = false; }
    const int h = hbase + hh;

    float blo[2], bhi[2];
#pragma unroll
    for (int p = 0; p < 2; ++p) {
        int d = pw * 32 + p * 16 + fr;     // in [0,64)
        blo[p] = bias[hh * 128 + d];
        bhi[p] = bias[hh * 128 + d + 64];
    }

#pragma unroll
    for (int mi = 0; mi < 8; ++mi) {
#pragma unroll
        for (int r = 0; r < 4; ++r) {
            int m = m0 + wm * 128 + mi * 16 + fq * 4 + r;   // C/D: row=quad*4+reg
            int b = m >> 12;                                // m / S
            int s = m & 4095;                               // m % S
            size_t orow = obase + ((size_t)(b * nh + h) * SS + s) * DD;
#pragma unroll
            for (int p = 0; p < 2; ++p) {
                int d = pw * 32 + p * 16 + fr;
                float xlo = acc[mi][2 * p][r] + blo[p];
                float xhi = acc[mi][2 * p + 1][r] + bhi[p];
                float ylo, yhi;
                if (rope) {
                    float c  = cosp[(size_t)m * DD + d];
                    float sn = sinp[(size_t)m * DD + d];
                    ylo = xlo * c - xhi * sn;      // d < 64:  x*cos - x_hi*sin
                    yhi = xhi * c + xlo * sn;      // d >= 64: x*cos + x_lo*sin
                } else {
                    ylo = xlo; yhi = xhi;
                }
                out[orow + d]      = ylo;
                out[orow + d + 64] = yhi;
            }
        }
    }
}

// ---------------------------------------------------------------- launch ----
extern "C" void kernel_launch(void* const* d_in, const int* in_sizes, int n_in,
                              void* d_out, int out_size, void* d_ws, size_t ws_size,
                              hipStream_t stream) {
    const float* hs   = (const float*)d_in[0];
    const float* cosp = (const float*)d_in[1];
    const float* sinp = (const float*)d_in[2];
    const float* Wq   = (const float*)d_in[3];
    const float* bq   = (const float*)d_in[4];
    const float* Wk   = (const float*)d_in[5];
    const float* bk   = (const float*)d_in[6];
    const float* Wv   = (const float*)d_in[7];
    const float* bv   = (const float*)d_in[8];
    float* out = (float*)d_out;

    bf16* Abf = (bf16*)d_ws;                      // 8192x3584 bf16 = 58.7 MB
    bf16* Btb = Abf + (size_t)MM * KK;            // 4608x3584 bf16 = 33.0 MB

    prep<<<NB_PREP, 256, 0, stream>>>(hs, Wq, Wk, Wv, Abf, Btb);
    qkv_gemm<<<GRID_GEMM, 512, 0, stream>>>(Abf, Btb, bq, bk, bv, cosp, sinp, out);
}